// Round 18
// baseline (1011.671 us; speedup 1.0000x reference)
//
#include <hip/hip_runtime.h>
#include <hip/hip_bf16.h>

#define Bn 32
#define Sn 400
#define Tn 100
#define Vn 32000
#define OOVn 100
#define VEn 32100
#define En 512
#define Un 256
#define AUn 256
#define GPn 256
#define ENCn 512
#define Z4n 1024
#define NPB 250

typedef __attribute__((ext_vector_type(8))) short bf16x8;
typedef __attribute__((ext_vector_type(4))) float f32x4;
typedef unsigned short ushort_t;
typedef unsigned long long u64;

__device__ __forceinline__ float rcp_f(float x){ return __builtin_amdgcn_rcpf(x); }
__device__ __forceinline__ float tanh_fast(float x){
  float e2 = __expf(2.f*x);
  return 1.f - 2.f*rcp_f(e2 + 1.f);
}
__device__ __forceinline__ float sigmoid_f(float x){ return 1.f/(1.f+__expf(-x)); }
__device__ __forceinline__ ushort_t f2bf(float f){
  unsigned u = __float_as_uint(f);
  unsigned r = (u + 0x7FFFu + ((u>>16)&1u)) >> 16;   // RNE
  return (ushort_t)r;
}
__device__ __forceinline__ u64 shfl_xor_u64(u64 v, int m){
  unsigned lo = (unsigned)v, hi = (unsigned)(v>>32);
  lo = (unsigned)__shfl_xor((int)lo, m);
  hi = (unsigned)__shfl_xor((int)hi, m);
  return ((u64)hi<<32)|(u64)lo;
}

// relaxed agent-scope ops: coherence-point loads/stores, no cache maintenance
__device__ __forceinline__ void st_rlx(float* p, float v){
  __hip_atomic_store(p, v, __ATOMIC_RELAXED, __HIP_MEMORY_SCOPE_AGENT);
}
__device__ __forceinline__ float ld_rlx(const float* p){
  return __hip_atomic_load(p, __ATOMIC_RELAXED, __HIP_MEMORY_SCOPE_AGENT);
}
__device__ __forceinline__ void st_rlxu(unsigned* p, unsigned v){
  __hip_atomic_store(p, v, __ATOMIC_RELAXED, __HIP_MEMORY_SCOPE_AGENT);
}
__device__ __forceinline__ void st_rlx64(u64* p, u64 v){
  __hip_atomic_store(p, v, __ATOMIC_RELAXED, __HIP_MEMORY_SCOPE_AGENT);
}
__device__ __forceinline__ u64 ld_rlx64(const u64* p){
  return __hip_atomic_load(p, __ATOMIC_RELAXED, __HIP_MEMORY_SCOPE_AGENT);
}
__device__ __forceinline__ void st_flag(unsigned* p, unsigned v){
  __hip_atomic_store(p, v, __ATOMIC_RELAXED, __HIP_MEMORY_SCOPE_AGENT);
}
__device__ __forceinline__ unsigned ld_flag(const unsigned* p){
  return __hip_atomic_load(p, __ATOMIC_RELAXED, __HIP_MEMORY_SCOPE_AGENT);
}

// ---------------- pre-loop: Zx = emb[gt] @ Wk + bias (fused gather) --------
// blocks (0,y) additionally zero bars/bars2/covloss.

__global__ __launch_bounds__(256) void k_zx(const int* __restrict__ gt,
    const float* __restrict__ emb, const float* __restrict__ Wk,
    const float* __restrict__ bias, float* __restrict__ Zx,
    unsigned* __restrict__ bars, unsigned* __restrict__ bars2,
    float* __restrict__ covloss){
  __shared__ float As[64][17];
  __shared__ float Bs[16][65];
  __shared__ int tok_lds[64];
  int r0 = blockIdx.x * 64;
  int c0 = blockIdx.y * 64;
  int tid = threadIdx.x;
  int ty = tid >> 4, tx16 = tid & 15;
  if (blockIdx.x == 0){
    int y = blockIdx.y;
    #pragma unroll
    for (int i = 0; i < 2; ++i){
      int idx = y*512 + i*256 + tid;
      bars[idx] = 0u;
      if (idx < NPB*32) bars2[idx] = 0u;
    }
    if (tid < 200) covloss[y*200 + tid] = 0.f;
  }
  if (tid < 64){
    int r = r0 + tid;
    tok_lds[tid] = gt[(r & 31)*Tn + (r >> 5)];
  }
  __syncthreads();
  float acc[4][4] = {};
  for (int k0 = 0; k0 < En; k0 += 16){
    #pragma unroll
    for (int p = 0; p < 4; ++p){
      int row = (tid>>4) + p*16, kk = tid & 15;
      As[row][kk] = emb[(size_t)tok_lds[row]*En + k0 + kk];
    }
    #pragma unroll
    for (int p = 0; p < 4; ++p){
      int kk = (tid>>6) + p*4, cc = tid & 63;
      Bs[kk][cc] = Wk[(size_t)(k0+kk)*Z4n + c0 + cc];
    }
    __syncthreads();
    #pragma unroll
    for (int kk = 0; kk < 16; ++kk){
      float av[4], bv[4];
      #pragma unroll
      for (int i=0;i<4;++i) av[i] = As[ty*4+i][kk];
      #pragma unroll
      for (int j=0;j<4;++j) bv[j] = Bs[kk][tx16*4+j];
      #pragma unroll
      for (int i=0;i<4;++i)
        #pragma unroll
        for (int j=0;j<4;++j) acc[i][j] += av[i]*bv[j];
    }
    __syncthreads();
  }
  #pragma unroll
  for (int i=0;i<4;++i){
    int row = r0 + ty*4 + i;
    #pragma unroll
    for (int j=0;j<4;++j){
      int col = c0 + tx16*4 + j;
      Zx[(size_t)row*Z4n + col] = acc[i][j] + bias[col];
    }
  }
}

// ---------------- persistent 256-block recurrent kernel (round-7 form) ----

__global__ __launch_bounds__(1024, 1) void k_loop(
    const float* __restrict__ Zx, const float* __restrict__ Wr,
    const float* __restrict__ Wd, const float* __restrict__ bd,
    const float* __restrict__ Wc, const float* __restrict__ Wa,
    const float* __restrict__ enc_attn,
    const float* __restrict__ h0, const float* __restrict__ c0,
    float* __restrict__ h_all, float* __restrict__ decp,
    float* __restrict__ c0_all, float* __restrict__ a_all,
    float* __restrict__ covloss, float* __restrict__ spart,
    unsigned* __restrict__ bars){
  __shared__ float Wr_lds[256*128];     // 128 KB: Wr cols {32k+i+256q}
  __shared__ float hfull[Un];
  __shared__ float ppart[8][132];
  __shared__ float zx_lds[128];
  __shared__ float zfull[128];
  __shared__ float hnew[32], cown[32];
  __shared__ float dec_lds[AUn];
  __shared__ float cov_lds[50], sc_lds[50];
  __shared__ float wred[16];
  __shared__ float red8[8];

  const int b = blockIdx.x & 31, k = blockIdx.x >> 5;
  const int tid = threadIdx.x, lane = tid & 63, w = tid >> 6;
  unsigned* flags = bars + b*8*32;          // 8 slots, 128 B apart
  unsigned* myflag = flags + k*32;

  for (int idx = tid; idx < 256*128; idx += 1024){
    int u = idx >> 7, jl = idx & 127;
    int gcol = 32*k + (jl & 31) + 256*(jl >> 5);
    Wr_lds[idx] = Wr[(size_t)u*Z4n + gcol];
  }
  if (tid < 32) cown[tid] = c0[b*Un + 32*k + tid];
  if (tid < 50) cov_lds[tid] = 0.f;
  const float4 wc4 = *(const float4*)(Wc + lane*4);
  const float4 wa4 = *(const float4*)(Wa + lane*4);
  if (tid < 256) hfull[tid] = h0[b*Un + tid];
  if (tid >= 256 && tid < 384){
    int jl = tid - 256;
    int gcol = 32*k + (jl & 31) + 256*(jl >> 5);
    zx_lds[jl] = Zx[(size_t)(0*Bn + b)*Z4n + gcol];
  }
  __syncthreads();

  // prestep
  {
    int p = tid >> 7, jl = tid & 127;
    float acc = 0.f;
    const float* wr = Wr_lds + (p*32)*128 + jl;
    const float* hb = hfull + p*32;
    #pragma unroll 8
    for (int uu = 0; uu < 32; ++uu) acc += hb[uu]*wr[uu*128];
    ppart[p][jl] = acc;
  }
  __syncthreads();
  if (tid < 128){
    float s = zx_lds[tid];
    #pragma unroll
    for (int q = 0; q < 8; ++q) s += ppart[q][tid];
    zfull[tid] = s;
  }
  __syncthreads();
  if (tid < 32){
    float zi = zfull[tid], zf = zfull[32+tid], zg = zfull[64+tid], zo = zfull[96+tid];
    float cn = sigmoid_f(zf)*cown[tid] + sigmoid_f(zi)*tanhf(zg);
    float hn = sigmoid_f(zo)*tanhf(cn);
    cown[tid] = cn; hnew[tid] = hn;
    int col = 32*k + tid;
    st_rlx(h_all + (size_t)(0*Bn + b)*Un + col, hn);
    if (b == 0) c0_all[0*Un + col] = cn;
  }
  __syncthreads();
  if (tid < 256){
    int c = tid;
    float acc = 0.f;
    const float* wdh = Wd + (size_t)(32*k)*AUn + c;
    #pragma unroll 8
    for (int u = 0; u < 32; ++u) acc += hnew[u]*wdh[(size_t)u*AUn];
    const float* wdc = Wd + (size_t)(Un + 32*k)*AUn + c;
    #pragma unroll 8
    for (int u = 0; u < 32; ++u) acc += cown[u]*wdc[(size_t)u*AUn];
    st_rlx(decp + (size_t)(b*8 + k)*256 + c, acc);   // slot 0
  }
  __syncthreads();
  if (tid == 0) st_flag(myflag, 1u);

  for (int t = 0; t < Tn; ++t){
    const int cur = t & 1, oth = cur ^ 1;
    if (tid < 8){
      while (ld_flag(flags + tid*32) < (unsigned)(t+1))
        __builtin_amdgcn_s_sleep(1);
    }
    __syncthreads();
    if (tid < 256){
      hfull[tid] = ld_rlx(h_all + (size_t)(t*Bn + b)*Un + tid);
    } else if (tid < 512){
      int c = tid - 256;
      float s = bd[c];
      const float* dp = decp + (size_t)cur*(Bn*8*256) + (size_t)(b*8)*256 + c;
      #pragma unroll
      for (int q = 0; q < 8; ++q) s += ld_rlx(dp + q*256);
      dec_lds[c] = s;
    } else if (tid < 520){
      red8[tid-512] = (t > 0) ? ld_rlx(spart + oth*(Bn*8) + b*8 + (tid-512)) : 0.f;
    } else if (tid >= 576 && tid < 704 && t + 1 < Tn){
      int jl = tid - 576;
      int gcol = 32*k + (jl & 31) + 256*(jl >> 5);
      zx_lds[jl] = Zx[(size_t)((t+1)*Bn + b)*Z4n + gcol];
    }
    __syncthreads();
    if (t > 0 && w == 0){
      float pv = (lane < 8) ? red8[lane] : 0.f;
      pv += __shfl_xor(pv, 1); pv += __shfl_xor(pv, 2); pv += __shfl_xor(pv, 4);
      float inv = 1.f / __shfl(pv, 0);
      float clp = 0.f;
      if (lane < 50){
        float aa = sc_lds[lane] * inv;
        float co = cov_lds[lane];
        a_all[(size_t)((t-1)*Bn + b)*Sn + 50*k + lane] = aa;
        clp = fminf(co, aa);
        cov_lds[lane] = co + aa;
      }
      #pragma unroll
      for (int m = 1; m < 64; m <<= 1) clp += __shfl_xor(clp, m);
      if (lane == 0) atomicAdd(&covloss[b*Tn + (t-1)], clp);
    }
    {
      int p = tid >> 7, jl = tid & 127;
      float acc = 0.f;
      const float* wr = Wr_lds + (p*32)*128 + jl;
      const float* hb = hfull + p*32;
      #pragma unroll 8
      for (int uu = 0; uu < 32; ++uu) acc += hb[uu]*wr[uu*128];
      ppart[p][jl] = acc;
    }
    __syncthreads();
    if (tid < 128 && t + 1 < Tn){
      float s = zx_lds[tid];
      #pragma unroll
      for (int q = 0; q < 8; ++q) s += ppart[q][tid];
      zfull[tid] = s;
    }
    __syncthreads();
    if (tid < 32 && t + 1 < Tn){
      float zi = zfull[tid], zf = zfull[32+tid], zg = zfull[64+tid], zo = zfull[96+tid];
      float cn = sigmoid_f(zf)*cown[tid] + sigmoid_f(zi)*tanhf(zg);
      float hn = sigmoid_f(zo)*tanhf(cn);
      cown[tid] = cn; hnew[tid] = hn;
      int col = 32*k + tid;
      st_rlx(h_all + (size_t)((t+1)*Bn + b)*Un + col, hn);
      if (b == 0) c0_all[(t+1)*Un + col] = cn;
    }
    __syncthreads();
    if (w < 4){
      if (t + 1 < Tn){
        int c = tid;
        float acc = 0.f;
        const float* wdh = Wd + (size_t)(32*k)*AUn + c;
        #pragma unroll 8
        for (int u = 0; u < 32; ++u) acc += hnew[u]*wdh[(size_t)u*AUn];
        const float* wdc = Wd + (size_t)(Un + 32*k)*AUn + c;
        #pragma unroll 8
        for (int u = 0; u < 32; ++u) acc += cown[u]*wdc[(size_t)u*AUn];
        st_rlx(decp + (size_t)oth*(Bn*8*256) + (size_t)(b*8 + k)*256 + c, acc);
      }
    } else {
      const float4 da = *(const float4*)(dec_lds + lane*4);
      float wsum = 0.f;
      for (int sl = w - 4; sl < 50; sl += 12){
        float cvv = cov_lds[sl];
        const float4 e = *(const float4*)(enc_attn + ((size_t)(b*Sn + 50*k + sl))*AUn + lane*4);
        float psc = tanh_fast(e.x + cvv*wc4.x + da.x)*wa4.x
                  + tanh_fast(e.y + cvv*wc4.y + da.y)*wa4.y
                  + tanh_fast(e.z + cvv*wc4.z + da.z)*wa4.z
                  + tanh_fast(e.w + cvv*wc4.w + da.w)*wa4.w;
        #pragma unroll
        for (int m = 1; m < 64; m <<= 1) psc += __shfl_xor(psc, m);
        if (lane == 0){
          float ev = __expf(psc);
          sc_lds[sl] = ev;
          wsum += ev;
        }
      }
      if (lane == 0) wred[w] = wsum;
    }
    __syncthreads();
    if (tid == 0){
      float S = 0.f;
      #pragma unroll
      for (int q = 4; q < 16; ++q) S += wred[q];
      st_rlx(spart + cur*(Bn*8) + b*8 + k, S);
    }
    __syncthreads();
    if (tid == 0) st_flag(myflag, (unsigned)(t + 2));
  }

  if (tid < 8){
    while (ld_flag(flags + tid*32) < (unsigned)(Tn + 1))
      __builtin_amdgcn_s_sleep(1);
  }
  __syncthreads();
  if (tid < 8) red8[tid] = ld_rlx(spart + ((Tn-1)&1)*(Bn*8) + b*8 + tid);
  __syncthreads();
  if (w == 0){
    float pv = (lane < 8) ? red8[lane] : 0.f;
    pv += __shfl_xor(pv, 1); pv += __shfl_xor(pv, 2); pv += __shfl_xor(pv, 4);
    float inv = 1.f / __shfl(pv, 0);
    float clp = 0.f;
    if (lane < 50){
      float aa = sc_lds[lane] * inv;
      float co = cov_lds[lane];
      a_all[(size_t)((Tn-1)*Bn + b)*Sn + 50*k + lane] = aa;
      clp = fminf(co, aa);
    }
    #pragma unroll
    for (int m = 1; m < 64; m <<= 1) clp += __shfl_xor(clp, m);
    if (lane == 0) atomicAdd(&covloss[b*Tn + (Tn-1)], clp);
  }
}

// ---------------- persistent epilogue: 250 blocks x 512 threads -----------
// stage1 {hid(gid<100), pg(100..199), W2 transpose (200..249)} -> BAR1 ->
// gemm0 (Sp partials) -> BAR2 -> Ssum reduce -> BAR3 -> gemm1 (probs plain
// stores + Ap partials). Scatter in a separate kernel (boundary coherence).

__global__ __launch_bounds__(512, 1) void k_post(
    const float* __restrict__ h_all, const float* __restrict__ W1,
    const float* __restrict__ b1, ushort_t* __restrict__ hid,
    const int* __restrict__ gt, const float* __restrict__ emb,
    const float* __restrict__ gpWi, const float* __restrict__ gpbi,
    const float* __restrict__ a_all, const float* __restrict__ enc_out,
    const float* __restrict__ c0_all, const float* __restrict__ gpWs,
    const float* __restrict__ gpWc, const float* __restrict__ gpWg,
    float* __restrict__ pg, const float* __restrict__ W2,
    ushort_t* __restrict__ W2T, const float* __restrict__ b2,
    float* __restrict__ Sp, float* __restrict__ Ssum, u64* __restrict__ Ap,
    float* __restrict__ probs, unsigned* __restrict__ bars2){
  __shared__ __align__(16) char sb[135168];
  __shared__ float red4[4];
  const int gid = blockIdx.x, tid = threadIdx.x;
  const int lane = tid & 63, w = tid >> 6;
  unsigned* myflag = bars2 + gid*32;

  // ======== stage 1 ========
  if (gid < 100){                 // hid[t], t = gid
    int t = gid;
    float* hl = (float*)sb;
    for (int i = tid; i < Bn*Un; i += 512) hl[i] = h_all[(size_t)t*Bn*Un + i];
    __syncthreads();
    int j = tid & 255, p = tid >> 8;
    float bj = b1[j];
    float acc[16];
    #pragma unroll
    for (int i = 0; i < 16; ++i) acc[i] = bj;
    for (int u = 0; u < Un; ++u){
      float wv = W1[u*Un + j];
      const float* hp = hl + (p*16)*Un + u;
      #pragma unroll
      for (int i = 0; i < 16; ++i) acc[i] += hp[i*Un] * wv;
    }
    __syncthreads();
    ushort_t* hidL = (ushort_t*)sb;
    #pragma unroll
    for (int i = 0; i < 16; ++i) hidL[(p*16+i)*Un + j] = f2bf(acc[i]);
    __syncthreads();
    unsigned* hw = (unsigned*)hid + (size_t)t*4096;
    const unsigned* hs = (const unsigned*)hidL;
    for (int i = tid; i < 4096; i += 512) st_rlxu(hw + i, hs[i]);
  } else if (gid < 200){          // pg[t], t = gid-100
    int t = gid - 100;
    float* al = (float*)sb;            // 400
    float* cv = al + 400;              // 512
    float* xl = cv + 512;              // 512
    for (int s = tid; s < Sn; s += 512) al[s] = a_all[(size_t)(t*Bn)*Sn + s];
    for (int i = tid; i < En; i += 512) xl[i] = emb[(size_t)gt[t]*En + i];
    __syncthreads();
    if (tid < ENCn){
      float acc = 0.f;
      for (int s = 0; s < Sn; ++s) acc += enc_out[(size_t)s*ENCn + tid]*al[s];
      cv[tid] = acc;
    }
    __syncthreads();
    if (tid < 256){
      int j = tid;
      float g = gpbi[j];
      for (int u = 0; u < En; ++u) g += xl[u]*gpWi[u*GPn + j];
      const float* h0r = h_all + (size_t)t*Bn*Un;     // b = 0 row
      const float* c0r = c0_all + t*Un;
      for (int u = 0; u < Un; ++u) g += h0r[u]*gpWs[u*GPn + j];
      for (int u = 0; u < Un; ++u) g += c0r[u]*gpWs[(Un+u)*GPn + j];
      for (int e = 0; e < ENCn; ++e) g += cv[e]*gpWc[e*GPn + j];
      float v = g * gpWg[j];
      #pragma unroll
      for (int m = 1; m < 64; m <<= 1) v += __shfl_xor(v, m);
      if (lane == 0) red4[w] = v;
    }
    __syncthreads();
    if (tid == 0)
      st_rlx(&pg[t], 1.f/(1.f+__expf(-(red4[0]+red4[1]+red4[2]+red4[3]))));
  } else {                        // W2 transpose: 40 tiles per block
    float (*tl)[65] = (float(*)[65])sb;
    int wblk = gid - 200;               // 0..49
    for (int rep = 0; rep < 40; ++rep){
      int tile = wblk*40 + rep;         // 0..1999
      int n0 = (tile % 500) * 64, k0 = (tile / 500) * 64;
      // load 64k x 64n tile (f32), coalesced over n
      {
        int kk = tid >> 6, nn = tid & 63;     // 8 k-rows per pass
        #pragma unroll
        for (int i = 0; i < 8; ++i)
          tl[kk + i*8][nn] = W2[(size_t)(k0 + kk + i*8)*Vn + n0 + nn];
      }
      __syncthreads();
      // write packed u32 (2 bf16 along k): W2T_u32[(n0+n)*128 + k0/2 + j]
      {
        int j = tid & 31, n16 = tid >> 5;     // 16 n-rows per pass
        unsigned* w32 = (unsigned*)W2T;
        #pragma unroll
        for (int i = 0; i < 4; ++i){
          int n = n16 + i*16;
          unsigned lo = f2bf(tl[2*j][n]);
          unsigned hi = f2bf(tl[2*j+1][n]);
          st_rlxu(&w32[(size_t)(n0+n)*128 + (k0>>1) + j], lo | (hi<<16));
        }
      }
      __syncthreads();
    }
  }
  // ---- BAR 1 ----
  __syncthreads();
  if (tid == 0) st_flag(myflag, 1u);
  if (tid < NPB){ while (ld_flag(bars2 + tid*32) < 1u) __builtin_amdgcn_s_sleep(1); }
  __syncthreads();

  // ======== gemm setup: stage B panel once ========
  ushort_t* Bs = (ushort_t*)sb;
  const int slice = gid % 125, gx = gid / 125;
  const int n0 = slice * 256;
  {
    int rr = tid >> 1, half = (tid & 1) * 128;
    const ushort_t* gb = W2T + (size_t)(n0 + rr)*Un + half;
    ushort_t* lb = Bs + rr*264 + half;
    #pragma unroll
    for (int j2 = 0; j2 < 16; ++j2)
      *((uint4*)lb + j2) = *((const uint4*)gb + j2);
  }
  __syncthreads();
  const int cbase = gx ? 13 : 0;
  const int nch   = gx ? 12 : 13;

  // ======== gemm pass 0: exp-sum partials Sp[slice][r] ========
  for (int ci = 0; ci < nch; ++ci){
    int r0 = (cbase + ci) * 128;
    bf16x8 af[8];
    {
      const ushort_t* ar = hid + (size_t)(r0 + w*16 + (lane&15))*Un + (lane>>4)*8;
      #pragma unroll
      for (int kk = 0; kk < 8; ++kk) af[kk] = *(const bf16x8*)(ar + kk*32);
    }
    f32x4 acc[16];
    #pragma unroll
    for (int i = 0; i < 16; ++i) acc[i] = (f32x4){0.f,0.f,0.f,0.f};
    #pragma unroll
    for (int kk = 0; kk < 8; ++kk){
      #pragma unroll
      for (int nt = 0; nt < 16; ++nt){
        bf16x8 bf = *(const bf16x8*)(Bs + (nt*16 + (lane&15))*264 + kk*32 + (lane>>4)*8);
        acc[nt] = __builtin_amdgcn_mfma_f32_16x16x32_bf16(af[kk], bf, acc[nt], 0, 0, 0);
      }
    }
    float rs[4] = {0.f,0.f,0.f,0.f};
    #pragma unroll
    for (int nt = 0; nt < 16; ++nt){
      int v = n0 + nt*16 + (lane&15);
      float b2v = b2[v];
      #pragma unroll
      for (int i = 0; i < 4; ++i) rs[i] += __expf(acc[nt][i] + b2v);
    }
    #pragma unroll
    for (int m = 1; m < 16; m <<= 1)
      #pragma unroll
      for (int i = 0; i < 4; ++i) rs[i] += __shfl_xor(rs[i], m);
    if ((lane&15) == 0){
      int rowloc = w*16 + (lane>>4)*4;
      #pragma unroll
      for (int i = 0; i < 4; ++i)
        st_rlx(&Sp[(size_t)slice*3200 + r0 + rowloc + i], rs[i]);
    }
  }
  // ---- BAR 2 ----
  __syncthreads();
  if (tid == 0) st_flag(myflag, 2u);
  if (tid < NPB){ while (ld_flag(bars2 + tid*32) < 2u) __builtin_amdgcn_s_sleep(1); }
  __syncthreads();

  // ======== Ssum reduce (blocks 0..6) ========
  if (gid < 7){
    int r = gid*512 + tid;
    if (r < 3200){
      float s = 0.f;
      for (int sl = 0; sl < 125; ++sl) s += ld_rlx(&Sp[(size_t)sl*3200 + r]);
      st_rlx(&Ssum[r], s);
    }
  }
  // ---- BAR 3 ----
  __syncthreads();
  if (tid == 0) st_flag(myflag, 3u);
  if (tid < NPB){ while (ld_flag(bars2 + tid*32) < 3u) __builtin_amdgcn_s_sleep(1); }
  __syncthreads();

  // ======== gemm pass 1: probs (PLAIN stores) + argmax partials Ap ========
  for (int ci = 0; ci < nch; ++ci){
    int r0 = (cbase + ci) * 128;
    bf16x8 af[8];
    {
      const ushort_t* ar = hid + (size_t)(r0 + w*16 + (lane&15))*Un + (lane>>4)*8;
      #pragma unroll
      for (int kk = 0; kk < 8; ++kk) af[kk] = *(const bf16x8*)(ar + kk*32);
    }
    f32x4 acc[16];
    #pragma unroll
    for (int i = 0; i < 16; ++i) acc[i] = (f32x4){0.f,0.f,0.f,0.f};
    #pragma unroll
    for (int kk = 0; kk < 8; ++kk){
      #pragma unroll
      for (int nt = 0; nt < 16; ++nt){
        bf16x8 bf = *(const bf16x8*)(Bs + (nt*16 + (lane&15))*264 + kk*32 + (lane>>4)*8);
        acc[nt] = __builtin_amdgcn_mfma_f32_16x16x32_bf16(af[kk], bf, acc[nt], 0, 0, 0);
      }
    }
    int rowloc = w*16 + (lane>>4)*4;
    float sc[4]; size_t obase[4];
    #pragma unroll
    for (int i = 0; i < 4; ++i){
      int r = r0 + rowloc + i; int tt = r>>5, bb = r&31;
      sc[i] = ld_rlx(&pg[tt]) / Ssum[r];
      obase[i] = (size_t)(bb*Tn + tt)*VEn;
    }
    u64 pm[4] = {0,0,0,0};
    #pragma unroll
    for (int nt = 0; nt < 16; ++nt){
      int v = n0 + nt*16 + (lane&15);
      float b2v = b2[v];
      #pragma unroll
      for (int i = 0; i < 4; ++i){
        float val = __expf(acc[nt][i] + b2v) * sc[i];
        probs[obase[i] + v] = val;
        u64 p = ((u64)__float_as_uint(val)<<32) | (u64)(0xFFFFFFFFu - (unsigned)v);
        pm[i] = p > pm[i] ? p : pm[i];
      }
    }
    #pragma unroll
    for (int m = 1; m < 16; m <<= 1)
      #pragma unroll
      for (int i = 0; i < 4; ++i){
        u64 o = shfl_xor_u64(pm[i], m);
        pm[i] = o > pm[i] ? o : pm[i];
      }
    if ((lane&15) == 0)
      #pragma unroll
      for (int i = 0; i < 4; ++i)
        st_rlx64(&Ap[(size_t)slice*3200 + r0 + rowloc + i], pm[i]);
  }
}

// scatter copy-dist via LDS hash dedup + OOV zeros + fused argmax -> seqs.
__global__ __launch_bounds__(256) void k_scatter(const int* __restrict__ ext,
    const float* __restrict__ a_all, const float* __restrict__ pg,
    float* __restrict__ probs, const u64* __restrict__ Ap,
    float* __restrict__ seqs){
  __shared__ int   hkey[1024];
  __shared__ float hval[1024];
  __shared__ u64   wmax[4];
  int r = blockIdx.x; int t = r>>5, b = r&31;
  float c1 = 1.f - pg[t];
  int tid = threadIdx.x;
  #pragma unroll
  for (int i = 0; i < 4; ++i){
    hkey[tid + i*256] = -1;
    hval[tid + i*256] = 0.f;
  }
  size_t obase = (size_t)(b*Tn + t)*VEn;
  if (tid < OOVn) probs[obase + Vn + tid] = 0.f;
  u64 vm = (tid < 125) ? Ap[(size_t)tid*3200 + r] : 0ull;
  __syncthreads();
  for (int s = tid; s < Sn; s += 256){
    int key = ext[b*Sn + s];
    float v = c1 * a_all[(size_t)r*Sn + s];
    unsigned h = ((unsigned)key * 2654435761u) >> 22;   // 10 bits
    for (;;){
      int old = atomicCAS(&hkey[h], -1, key);
      if (old == -1 || old == key) break;
      h = (h + 1) & 1023;
    }
    atomicAdd(&hval[h], v);
  }
  __syncthreads();
  u64 pm = vm;
  #pragma unroll
  for (int i = 0; i < 4; ++i){
    int slot = tid + i*256;
    int tk = hkey[slot];
    if (tk >= 0){
      float nv = probs[obase + tk] + hval[slot];
      probs[obase + tk] = nv;
      u64 p = ((u64)__float_as_uint(nv)<<32) | (u64)(0xFFFFFFFFu - (unsigned)tk);
      pm = p > pm ? p : pm;
    }
  }
  #pragma unroll
  for (int m = 1; m < 64; m <<= 1){
    u64 o = shfl_xor_u64(pm, m);
    pm = o > pm ? o : pm;
  }
  int lane = tid & 63, w = tid >> 6;
  if (lane == 0) wmax[w] = pm;
  __syncthreads();
  if (tid == 0){
    u64 mm = wmax[0];
    #pragma unroll
    for (int q = 1; q < 4; ++q) mm = wmax[q] > mm ? wmax[q] : mm;
    unsigned tk = 0xFFFFFFFFu - (unsigned)(mm & 0xFFFFFFFFull);
    seqs[b*Tn + t] = (float)tk;
  }
}

// ---------------- host launch ----------------

extern "C" void kernel_launch(void* const* d_in, const int* in_sizes, int n_in,
                              void* d_out, int out_size, void* d_ws, size_t ws_size,
                              hipStream_t stream){
  (void)in_sizes; (void)n_in; (void)out_size; (void)ws_size;
  const int*   gt       = (const int*)d_in[0];
  const int*   ext      = (const int*)d_in[1];
  const float* enc_out  = (const float*)d_in[2];
  const float* enc_attn = (const float*)d_in[3];
  const float* h0       = (const float*)d_in[4];
  const float* c0       = (const float*)d_in[5];
  const float* emb      = (const float*)d_in[6];
  const float* Wk       = (const float*)d_in[7];
  const float* Wr       = (const float*)d_in[8];
  const float* lb       = (const float*)d_in[9];
  const float* Wd       = (const float*)d_in[10];
  const float* bd       = (const float*)d_in[11];
  const float* Wc       = (const float*)d_in[12];
  const float* Wa       = (const float*)d_in[13];
  const float* W1       = (const float*)d_in[14];
  const float* b1       = (const float*)d_in[15];
  const float* W2       = (const float*)d_in[16];
  const float* b2       = (const float*)d_in[17];
  const float* gpWs     = (const float*)d_in[18];
  const float* gpWc     = (const float*)d_in[19];
  const float* gpWi     = (const float*)d_in[20];
  const float* gpbi     = (const float*)d_in[21];
  const float* gpWg     = (const float*)d_in[22];

  float* probs   = (float*)d_out;
  float* seqs    = probs + (size_t)Bn*Tn*VEn;
  float* covloss = seqs + Bn*Tn;

  char* wp = (char*)d_ws;
  auto carve = [&](size_t bytes)->void*{
    void* p = (void*)wp; wp += (bytes + 255) & ~(size_t)255; return p;
  };
  float*    Zx      = (float*)carve((size_t)3200*Z4n*4);
  float*    h_all   = (float*)carve((size_t)Tn*Bn*Un*4);
  float*    decp    = (float*)carve((size_t)2*Bn*8*256*4);
  float*    c0_all  = (float*)carve((size_t)Tn*Un*4);
  float*    a_all   = (float*)carve((size_t)3200*Sn*4);
  ushort_t* hid_bf  = (ushort_t*)carve((size_t)3200*Un*2);
  ushort_t* W2T     = (ushort_t*)carve((size_t)Vn*Un*2);
  float*    Ssum    = (float*)carve((size_t)3200*4);
  float*    Sp      = (float*)carve((size_t)125*3200*4);
  u64*      Ap      = (u64*)carve((size_t)125*3200*8);
  float*    pg      = (float*)carve((size_t)Tn*4);
  float*    spart   = (float*)carve((size_t)2*Bn*8*4);
  unsigned* bars    = (unsigned*)carve((size_t)Bn*8*32*4);
  unsigned* bars2   = (unsigned*)carve((size_t)NPB*32*4);

  k_zx  <<<dim3(50,16), 256, 0, stream>>>(gt, emb, Wk, lb, Zx,
                                          bars, bars2, covloss);

  k_loop<<<256, 1024, 0, stream>>>(Zx, Wr, Wd, bd, Wc, Wa, enc_attn,
                                   h0, c0, h_all, decp, c0_all,
                                   a_all, covloss, spart, bars);

  k_post<<<NPB, 512, 0, stream>>>(h_all, W1, b1, hid_bf, gt, emb,
                                  gpWi, gpbi, a_all, enc_out, c0_all,
                                  gpWs, gpWc, gpWg, pg, W2, W2T, b2,
                                  Sp, Ssum, Ap, probs, bars2);

  k_scatter<<<3200, 256, 0, stream>>>(ext, a_all, pg, probs, Ap, seqs);
}

// Round 19
// 994.972 us; speedup vs baseline: 1.0168x; 1.0168x over previous
//
#include <hip/hip_runtime.h>
#include <hip/hip_bf16.h>

#define Bn 32
#define Sn 400
#define Tn 100
#define Vn 32000
#define OOVn 100
#define VEn 32100
#define En 512
#define Un 256
#define AUn 256
#define GPn 256
#define ENCn 512
#define Z4n 1024
#define NPB 250
#define WRP 260   // padded col stride for transposed Wr (256 + 4)

typedef __attribute__((ext_vector_type(8))) short bf16x8;
typedef __attribute__((ext_vector_type(4))) float f32x4;
typedef unsigned short ushort_t;
typedef unsigned long long u64;

__device__ __forceinline__ float rcp_f(float x){ return __builtin_amdgcn_rcpf(x); }
__device__ __forceinline__ float tanh_fast(float x){
  float e2 = __expf(2.f*x);
  return 1.f - 2.f*rcp_f(e2 + 1.f);
}
__device__ __forceinline__ float sigmoid_f(float x){ return 1.f/(1.f+__expf(-x)); }
__device__ __forceinline__ ushort_t f2bf(float f){
  unsigned u = __float_as_uint(f);
  unsigned r = (u + 0x7FFFu + ((u>>16)&1u)) >> 16;   // RNE
  return (ushort_t)r;
}
__device__ __forceinline__ u64 shfl_xor_u64(u64 v, int m){
  unsigned lo = (unsigned)v, hi = (unsigned)(v>>32);
  lo = (unsigned)__shfl_xor((int)lo, m);
  hi = (unsigned)__shfl_xor((int)hi, m);
  return ((u64)hi<<32)|(u64)lo;
}

// relaxed agent-scope ops: coherence-point loads/stores, no cache maintenance
__device__ __forceinline__ void st_rlx(float* p, float v){
  __hip_atomic_store(p, v, __ATOMIC_RELAXED, __HIP_MEMORY_SCOPE_AGENT);
}
__device__ __forceinline__ float ld_rlx(const float* p){
  return __hip_atomic_load(p, __ATOMIC_RELAXED, __HIP_MEMORY_SCOPE_AGENT);
}
__device__ __forceinline__ void st_rlxu(unsigned* p, unsigned v){
  __hip_atomic_store(p, v, __ATOMIC_RELAXED, __HIP_MEMORY_SCOPE_AGENT);
}
__device__ __forceinline__ void st_rlx64(u64* p, u64 v){
  __hip_atomic_store(p, v, __ATOMIC_RELAXED, __HIP_MEMORY_SCOPE_AGENT);
}
__device__ __forceinline__ u64 ld_rlx64(const u64* p){
  return __hip_atomic_load(p, __ATOMIC_RELAXED, __HIP_MEMORY_SCOPE_AGENT);
}
__device__ __forceinline__ void st_flag(unsigned* p, unsigned v){
  __hip_atomic_store(p, v, __ATOMIC_RELAXED, __HIP_MEMORY_SCOPE_AGENT);
}
__device__ __forceinline__ unsigned ld_flag(const unsigned* p){
  return __hip_atomic_load(p, __ATOMIC_RELAXED, __HIP_MEMORY_SCOPE_AGENT);
}

// ---------------- pre-loop: Zx = emb[gt] @ Wk + bias (fused gather) --------
// blocks (0,y) additionally zero bars/bars2/covloss.

__global__ __launch_bounds__(256) void k_zx(const int* __restrict__ gt,
    const float* __restrict__ emb, const float* __restrict__ Wk,
    const float* __restrict__ bias, float* __restrict__ Zx,
    unsigned* __restrict__ bars, unsigned* __restrict__ bars2,
    float* __restrict__ covloss){
  __shared__ float As[64][17];
  __shared__ float Bs[16][65];
  __shared__ int tok_lds[64];
  int r0 = blockIdx.x * 64;
  int c0 = blockIdx.y * 64;
  int tid = threadIdx.x;
  int ty = tid >> 4, tx16 = tid & 15;
  if (blockIdx.x == 0){
    int y = blockIdx.y;
    #pragma unroll
    for (int i = 0; i < 2; ++i){
      int idx = y*512 + i*256 + tid;
      bars[idx] = 0u;
      if (idx < NPB*32) bars2[idx] = 0u;
    }
    if (tid < 200) covloss[y*200 + tid] = 0.f;
  }
  if (tid < 64){
    int r = r0 + tid;
    tok_lds[tid] = gt[(r & 31)*Tn + (r >> 5)];
  }
  __syncthreads();
  float acc[4][4] = {};
  for (int k0 = 0; k0 < En; k0 += 16){
    #pragma unroll
    for (int p = 0; p < 4; ++p){
      int row = (tid>>4) + p*16, kk = tid & 15;
      As[row][kk] = emb[(size_t)tok_lds[row]*En + k0 + kk];
    }
    #pragma unroll
    for (int p = 0; p < 4; ++p){
      int kk = (tid>>6) + p*4, cc = tid & 63;
      Bs[kk][cc] = Wk[(size_t)(k0+kk)*Z4n + c0 + cc];
    }
    __syncthreads();
    #pragma unroll
    for (int kk = 0; kk < 16; ++kk){
      float av[4], bv[4];
      #pragma unroll
      for (int i=0;i<4;++i) av[i] = As[ty*4+i][kk];
      #pragma unroll
      for (int j=0;j<4;++j) bv[j] = Bs[kk][tx16*4+j];
      #pragma unroll
      for (int i=0;i<4;++i)
        #pragma unroll
        for (int j=0;j<4;++j) acc[i][j] += av[i]*bv[j];
    }
    __syncthreads();
  }
  #pragma unroll
  for (int i=0;i<4;++i){
    int row = r0 + ty*4 + i;
    #pragma unroll
    for (int j=0;j<4;++j){
      int col = c0 + tx16*4 + j;
      Zx[(size_t)row*Z4n + col] = acc[i][j] + bias[col];
    }
  }
}

// ---------------- persistent 256-block recurrent kernel -------------------
// Round-7 protocol; Wr transposed in LDS ([jl][WRP]) for ds_read_b128 in P2.

__global__ __launch_bounds__(1024, 1) void k_loop(
    const float* __restrict__ Zx, const float* __restrict__ Wr,
    const float* __restrict__ Wd, const float* __restrict__ bd,
    const float* __restrict__ Wc, const float* __restrict__ Wa,
    const float* __restrict__ enc_attn,
    const float* __restrict__ h0, const float* __restrict__ c0,
    float* __restrict__ h_all, float* __restrict__ decp,
    float* __restrict__ c0_all, float* __restrict__ a_all,
    float* __restrict__ covloss, float* __restrict__ spart,
    unsigned* __restrict__ bars){
  __shared__ float Wr_lds[128*WRP];     // 133,120 B: Wr col jl, u contiguous
  __shared__ float hfull[Un];
  __shared__ float ppart[8][132];
  __shared__ float zx_lds[128];
  __shared__ float zfull[128];
  __shared__ float hnew[32], cown[32];
  __shared__ float dec_lds[AUn];
  __shared__ float cov_lds[50], sc_lds[50];
  __shared__ float wred[16];
  __shared__ float red8[8];

  const int b = blockIdx.x & 31, k = blockIdx.x >> 5;
  const int tid = threadIdx.x, lane = tid & 63, w = tid >> 6;
  unsigned* flags = bars + b*8*32;          // 8 slots, 128 B apart
  unsigned* myflag = flags + k*32;

  // transposed fill: consecutive tid -> consecutive jl (coalesced global)
  for (int idx = tid; idx < 128*256; idx += 1024){
    int jl = idx & 127, u = idx >> 7;
    int gcol = 32*k + (jl & 31) + 256*(jl >> 5);
    Wr_lds[jl*WRP + u] = Wr[(size_t)u*Z4n + gcol];
  }
  if (tid < 32) cown[tid] = c0[b*Un + 32*k + tid];
  if (tid < 50) cov_lds[tid] = 0.f;
  const float4 wc4 = *(const float4*)(Wc + lane*4);
  const float4 wa4 = *(const float4*)(Wa + lane*4);
  if (tid < 256) hfull[tid] = h0[b*Un + tid];
  if (tid >= 256 && tid < 384){
    int jl = tid - 256;
    int gcol = 32*k + (jl & 31) + 256*(jl >> 5);
    zx_lds[jl] = Zx[(size_t)(0*Bn + b)*Z4n + gcol];
  }
  __syncthreads();

  // prestep
  {
    int p = tid >> 7, jl = tid & 127;
    const float* wr = Wr_lds + jl*WRP + p*32;
    const float* hb = hfull + p*32;
    float acc = 0.f;
    #pragma unroll
    for (int c = 0; c < 8; ++c){
      float4 wv = *(const float4*)(wr + 4*c);
      float4 hv = *(const float4*)(hb + 4*c);
      acc += wv.x*hv.x + wv.y*hv.y + wv.z*hv.z + wv.w*hv.w;
    }
    ppart[p][jl] = acc;
  }
  __syncthreads();
  if (tid < 128){
    float s = zx_lds[tid];
    #pragma unroll
    for (int q = 0; q < 8; ++q) s += ppart[q][tid];
    zfull[tid] = s;
  }
  __syncthreads();
  if (tid < 32){
    float zi = zfull[tid], zf = zfull[32+tid], zg = zfull[64+tid], zo = zfull[96+tid];
    float cn = sigmoid_f(zf)*cown[tid] + sigmoid_f(zi)*tanhf(zg);
    float hn = sigmoid_f(zo)*tanhf(cn);
    cown[tid] = cn; hnew[tid] = hn;
    int col = 32*k + tid;
    st_rlx(h_all + (size_t)(0*Bn + b)*Un + col, hn);
    if (b == 0) c0_all[0*Un + col] = cn;
  }
  __syncthreads();
  if (tid < 256){
    int c = tid;
    float acc = 0.f;
    const float* wdh = Wd + (size_t)(32*k)*AUn + c;
    #pragma unroll 8
    for (int u = 0; u < 32; ++u) acc += hnew[u]*wdh[(size_t)u*AUn];
    const float* wdc = Wd + (size_t)(Un + 32*k)*AUn + c;
    #pragma unroll 8
    for (int u = 0; u < 32; ++u) acc += cown[u]*wdc[(size_t)u*AUn];
    st_rlx(decp + (size_t)(b*8 + k)*256 + c, acc);   // slot 0
  }
  __syncthreads();
  if (tid == 0) st_flag(myflag, 1u);

  for (int t = 0; t < Tn; ++t){
    const int cur = t & 1, oth = cur ^ 1;
    if (tid < 8){
      while (ld_flag(flags + tid*32) < (unsigned)(t+1))
        __builtin_amdgcn_s_sleep(1);
    }
    __syncthreads();
    if (tid < 256){
      hfull[tid] = ld_rlx(h_all + (size_t)(t*Bn + b)*Un + tid);
    } else if (tid < 512){
      int c = tid - 256;
      float s = bd[c];
      const float* dp = decp + (size_t)cur*(Bn*8*256) + (size_t)(b*8)*256 + c;
      #pragma unroll
      for (int q = 0; q < 8; ++q) s += ld_rlx(dp + q*256);
      dec_lds[c] = s;
    } else if (tid < 520){
      red8[tid-512] = (t > 0) ? ld_rlx(spart + oth*(Bn*8) + b*8 + (tid-512)) : 0.f;
    } else if (tid >= 576 && tid < 704 && t + 1 < Tn){
      int jl = tid - 576;
      int gcol = 32*k + (jl & 31) + 256*(jl >> 5);
      zx_lds[jl] = Zx[(size_t)((t+1)*Bn + b)*Z4n + gcol];
    }
    __syncthreads();
    // P2: softmax-finish(t-1) on wave 0 ; LSTM partials (b128) on all waves
    if (t > 0 && w == 0){
      float pv = (lane < 8) ? red8[lane] : 0.f;
      pv += __shfl_xor(pv, 1); pv += __shfl_xor(pv, 2); pv += __shfl_xor(pv, 4);
      float inv = 1.f / __shfl(pv, 0);
      float clp = 0.f;
      if (lane < 50){
        float aa = sc_lds[lane] * inv;
        float co = cov_lds[lane];
        a_all[(size_t)((t-1)*Bn + b)*Sn + 50*k + lane] = aa;
        clp = fminf(co, aa);
        cov_lds[lane] = co + aa;
      }
      #pragma unroll
      for (int m = 1; m < 64; m <<= 1) clp += __shfl_xor(clp, m);
      if (lane == 0) atomicAdd(&covloss[b*Tn + (t-1)], clp);
    }
    {
      int p = tid >> 7, jl = tid & 127;
      const float* wr = Wr_lds + jl*WRP + p*32;
      const float* hb = hfull + p*32;
      float acc = 0.f;
      #pragma unroll
      for (int c = 0; c < 8; ++c){
        float4 wv = *(const float4*)(wr + 4*c);
        float4 hv = *(const float4*)(hb + 4*c);
        acc += wv.x*hv.x + wv.y*hv.y + wv.z*hv.z + wv.w*hv.w;
      }
      ppart[p][jl] = acc;
    }
    __syncthreads();
    if (tid < 128 && t + 1 < Tn){
      float s = zx_lds[tid];
      #pragma unroll
      for (int q = 0; q < 8; ++q) s += ppart[q][tid];
      zfull[tid] = s;
    }
    __syncthreads();
    if (tid < 32 && t + 1 < Tn){
      float zi = zfull[tid], zf = zfull[32+tid], zg = zfull[64+tid], zo = zfull[96+tid];
      float cn = sigmoid_f(zf)*cown[tid] + sigmoid_f(zi)*tanhf(zg);
      float hn = sigmoid_f(zo)*tanhf(cn);
      cown[tid] = cn; hnew[tid] = hn;
      int col = 32*k + tid;
      st_rlx(h_all + (size_t)((t+1)*Bn + b)*Un + col, hn);
      if (b == 0) c0_all[(t+1)*Un + col] = cn;
    }
    __syncthreads();
    if (w < 4){
      if (t + 1 < Tn){
        int c = tid;
        float acc = 0.f;
        const float* wdh = Wd + (size_t)(32*k)*AUn + c;
        #pragma unroll 8
        for (int u = 0; u < 32; ++u) acc += hnew[u]*wdh[(size_t)u*AUn];
        const float* wdc = Wd + (size_t)(Un + 32*k)*AUn + c;
        #pragma unroll 8
        for (int u = 0; u < 32; ++u) acc += cown[u]*wdc[(size_t)u*AUn];
        st_rlx(decp + (size_t)oth*(Bn*8*256) + (size_t)(b*8 + k)*256 + c, acc);
      }
    } else {
      const float4 da = *(const float4*)(dec_lds + lane*4);
      float wsum = 0.f;
      for (int sl = w - 4; sl < 50; sl += 12){
        float cvv = cov_lds[sl];
        const float4 e = *(const float4*)(enc_attn + ((size_t)(b*Sn + 50*k + sl))*AUn + lane*4);
        float psc = tanh_fast(e.x + cvv*wc4.x + da.x)*wa4.x
                  + tanh_fast(e.y + cvv*wc4.y + da.y)*wa4.y
                  + tanh_fast(e.z + cvv*wc4.z + da.z)*wa4.z
                  + tanh_fast(e.w + cvv*wc4.w + da.w)*wa4.w;
        #pragma unroll
        for (int m = 1; m < 64; m <<= 1) psc += __shfl_xor(psc, m);
        if (lane == 0){
          float ev = __expf(psc);
          sc_lds[sl] = ev;
          wsum += ev;
        }
      }
      if (lane == 0) wred[w] = wsum;
    }
    __syncthreads();
    if (tid == 0){
      float S = 0.f;
      #pragma unroll
      for (int q = 4; q < 16; ++q) S += wred[q];
      st_rlx(spart + cur*(Bn*8) + b*8 + k, S);
    }
    __syncthreads();
    if (tid == 0) st_flag(myflag, (unsigned)(t + 2));
  }

  if (tid < 8){
    while (ld_flag(flags + tid*32) < (unsigned)(Tn + 1))
      __builtin_amdgcn_s_sleep(1);
  }
  __syncthreads();
  if (tid < 8) red8[tid] = ld_rlx(spart + ((Tn-1)&1)*(Bn*8) + b*8 + tid);
  __syncthreads();
  if (w == 0){
    float pv = (lane < 8) ? red8[lane] : 0.f;
    pv += __shfl_xor(pv, 1); pv += __shfl_xor(pv, 2); pv += __shfl_xor(pv, 4);
    float inv = 1.f / __shfl(pv, 0);
    float clp = 0.f;
    if (lane < 50){
      float aa = sc_lds[lane] * inv;
      float co = cov_lds[lane];
      a_all[(size_t)((Tn-1)*Bn + b)*Sn + 50*k + lane] = aa;
      clp = fminf(co, aa);
    }
    #pragma unroll
    for (int m = 1; m < 64; m <<= 1) clp += __shfl_xor(clp, m);
    if (lane == 0) atomicAdd(&covloss[b*Tn + (Tn-1)], clp);
  }
}

// ---------------- persistent epilogue: 250 blocks x 512 threads -----------
// stage1 {hid(gid<100), pg(100..199), W2 transpose (200..249)} -> BAR1 ->
// gemm0 (Sp partials) -> BAR2 -> Ssum reduce -> BAR3 -> gemm1 (probs plain
// stores + Ap partials). Scatter in a separate kernel (boundary coherence).

__global__ __launch_bounds__(512, 1) void k_post(
    const float* __restrict__ h_all, const float* __restrict__ W1,
    const float* __restrict__ b1, ushort_t* __restrict__ hid,
    const int* __restrict__ gt, const float* __restrict__ emb,
    const float* __restrict__ gpWi, const float* __restrict__ gpbi,
    const float* __restrict__ a_all, const float* __restrict__ enc_out,
    const float* __restrict__ c0_all, const float* __restrict__ gpWs,
    const float* __restrict__ gpWc, const float* __restrict__ gpWg,
    float* __restrict__ pg, const float* __restrict__ W2,
    ushort_t* __restrict__ W2T, const float* __restrict__ b2,
    float* __restrict__ Sp, float* __restrict__ Ssum, u64* __restrict__ Ap,
    float* __restrict__ probs, unsigned* __restrict__ bars2){
  __shared__ __align__(16) char sb[135168];
  __shared__ float red4[4];
  const int gid = blockIdx.x, tid = threadIdx.x;
  const int lane = tid & 63, w = tid >> 6;
  unsigned* myflag = bars2 + gid*32;

  // ======== stage 1 ========
  if (gid < 100){                 // hid[t], t = gid
    int t = gid;
    float* hl = (float*)sb;
    for (int i = tid; i < Bn*Un; i += 512) hl[i] = h_all[(size_t)t*Bn*Un + i];
    __syncthreads();
    int j = tid & 255, p = tid >> 8;
    float bj = b1[j];
    float acc[16];
    #pragma unroll
    for (int i = 0; i < 16; ++i) acc[i] = bj;
    for (int u = 0; u < Un; ++u){
      float wv = W1[u*Un + j];
      const float* hp = hl + (p*16)*Un + u;
      #pragma unroll
      for (int i = 0; i < 16; ++i) acc[i] += hp[i*Un] * wv;
    }
    __syncthreads();
    ushort_t* hidL = (ushort_t*)sb;
    #pragma unroll
    for (int i = 0; i < 16; ++i) hidL[(p*16+i)*Un + j] = f2bf(acc[i]);
    __syncthreads();
    unsigned* hw = (unsigned*)hid + (size_t)t*4096;
    const unsigned* hs = (const unsigned*)hidL;
    for (int i = tid; i < 4096; i += 512) st_rlxu(hw + i, hs[i]);
  } else if (gid < 200){          // pg[t], t = gid-100
    int t = gid - 100;
    float* al = (float*)sb;            // 400
    float* cv = al + 400;              // 512
    float* xl = cv + 512;              // 512
    for (int s = tid; s < Sn; s += 512) al[s] = a_all[(size_t)(t*Bn)*Sn + s];
    for (int i = tid; i < En; i += 512) xl[i] = emb[(size_t)gt[t]*En + i];
    __syncthreads();
    if (tid < ENCn){
      float acc = 0.f;
      for (int s = 0; s < Sn; ++s) acc += enc_out[(size_t)s*ENCn + tid]*al[s];
      cv[tid] = acc;
    }
    __syncthreads();
    if (tid < 256){
      int j = tid;
      float g = gpbi[j];
      for (int u = 0; u < En; ++u) g += xl[u]*gpWi[u*GPn + j];
      const float* h0r = h_all + (size_t)t*Bn*Un;     // b = 0 row
      const float* c0r = c0_all + t*Un;
      for (int u = 0; u < Un; ++u) g += h0r[u]*gpWs[u*GPn + j];
      for (int u = 0; u < Un; ++u) g += c0r[u]*gpWs[(Un+u)*GPn + j];
      for (int e = 0; e < ENCn; ++e) g += cv[e]*gpWc[e*GPn + j];
      float v = g * gpWg[j];
      #pragma unroll
      for (int m = 1; m < 64; m <<= 1) v += __shfl_xor(v, m);
      if (lane == 0) red4[w] = v;
    }
    __syncthreads();
    if (tid == 0)
      st_rlx(&pg[t], 1.f/(1.f+__expf(-(red4[0]+red4[1]+red4[2]+red4[3]))));
  } else {                        // W2 transpose: 40 tiles per block
    float (*tl)[65] = (float(*)[65])sb;
    int wblk = gid - 200;               // 0..49
    for (int rep = 0; rep < 40; ++rep){
      int tile = wblk*40 + rep;         // 0..1999
      int n0 = (tile % 500) * 64, k0 = (tile / 500) * 64;
      {
        int kk = tid >> 6, nn = tid & 63;     // 8 k-rows per pass
        #pragma unroll
        for (int i = 0; i < 8; ++i)
          tl[kk + i*8][nn] = W2[(size_t)(k0 + kk + i*8)*Vn + n0 + nn];
      }
      __syncthreads();
      {
        int j = tid & 31, n16 = tid >> 5;     // 16 n-rows per pass
        unsigned* w32 = (unsigned*)W2T;
        #pragma unroll
        for (int i = 0; i < 4; ++i){
          int n = n16 + i*16;
          unsigned lo = f2bf(tl[2*j][n]);
          unsigned hi = f2bf(tl[2*j+1][n]);
          st_rlxu(&w32[(size_t)(n0+n)*128 + (k0>>1) + j], lo | (hi<<16));
        }
      }
      __syncthreads();
    }
  }
  // ---- BAR 1 ----
  __syncthreads();
  if (tid == 0) st_flag(myflag, 1u);
  if (tid < NPB){ while (ld_flag(bars2 + tid*32) < 1u) __builtin_amdgcn_s_sleep(1); }
  __syncthreads();

  // ======== gemm setup: stage B panel once ========
  ushort_t* Bs = (ushort_t*)sb;
  const int slice = gid % 125, gx = gid / 125;
  const int n0 = slice * 256;
  {
    int rr = tid >> 1, half = (tid & 1) * 128;
    const ushort_t* gb = W2T + (size_t)(n0 + rr)*Un + half;
    ushort_t* lb = Bs + rr*264 + half;
    #pragma unroll
    for (int j2 = 0; j2 < 16; ++j2)
      *((uint4*)lb + j2) = *((const uint4*)gb + j2);
  }
  __syncthreads();
  const int cbase = gx ? 13 : 0;
  const int nch   = gx ? 12 : 13;

  // ======== gemm pass 0: exp-sum partials Sp[slice][r] ========
  for (int ci = 0; ci < nch; ++ci){
    int r0 = (cbase + ci) * 128;
    bf16x8 af[8];
    {
      const ushort_t* ar = hid + (size_t)(r0 + w*16 + (lane&15))*Un + (lane>>4)*8;
      #pragma unroll
      for (int kk = 0; kk < 8; ++kk) af[kk] = *(const bf16x8*)(ar + kk*32);
    }
    f32x4 acc[16];
    #pragma unroll
    for (int i = 0; i < 16; ++i) acc[i] = (f32x4){0.f,0.f,0.f,0.f};
    #pragma unroll
    for (int kk = 0; kk < 8; ++kk){
      #pragma unroll
      for (int nt = 0; nt < 16; ++nt){
        bf16x8 bf = *(const bf16x8*)(Bs + (nt*16 + (lane&15))*264 + kk*32 + (lane>>4)*8);
        acc[nt] = __builtin_amdgcn_mfma_f32_16x16x32_bf16(af[kk], bf, acc[nt], 0, 0, 0);
      }
    }
    float rs[4] = {0.f,0.f,0.f,0.f};
    #pragma unroll
    for (int nt = 0; nt < 16; ++nt){
      int v = n0 + nt*16 + (lane&15);
      float b2v = b2[v];
      #pragma unroll
      for (int i = 0; i < 4; ++i) rs[i] += __expf(acc[nt][i] + b2v);
    }
    #pragma unroll
    for (int m = 1; m < 16; m <<= 1)
      #pragma unroll
      for (int i = 0; i < 4; ++i) rs[i] += __shfl_xor(rs[i], m);
    if ((lane&15) == 0){
      int rowloc = w*16 + (lane>>4)*4;
      #pragma unroll
      for (int i = 0; i < 4; ++i)
        st_rlx(&Sp[(size_t)slice*3200 + r0 + rowloc + i], rs[i]);
    }
  }
  // ---- BAR 2 ----
  __syncthreads();
  if (tid == 0) st_flag(myflag, 2u);
  if (tid < NPB){ while (ld_flag(bars2 + tid*32) < 2u) __builtin_amdgcn_s_sleep(1); }
  __syncthreads();

  // ======== Ssum reduce (blocks 0..6) ========
  if (gid < 7){
    int r = gid*512 + tid;
    if (r < 3200){
      float s = 0.f;
      for (int sl = 0; sl < 125; ++sl) s += ld_rlx(&Sp[(size_t)sl*3200 + r]);
      st_rlx(&Ssum[r], s);
    }
  }
  // ---- BAR 3 ----
  __syncthreads();
  if (tid == 0) st_flag(myflag, 3u);
  if (tid < NPB){ while (ld_flag(bars2 + tid*32) < 3u) __builtin_amdgcn_s_sleep(1); }
  __syncthreads();

  // ======== gemm pass 1: probs (PLAIN stores) + argmax partials Ap ========
  for (int ci = 0; ci < nch; ++ci){
    int r0 = (cbase + ci) * 128;
    bf16x8 af[8];
    {
      const ushort_t* ar = hid + (size_t)(r0 + w*16 + (lane&15))*Un + (lane>>4)*8;
      #pragma unroll
      for (int kk = 0; kk < 8; ++kk) af[kk] = *(const bf16x8*)(ar + kk*32);
    }
    f32x4 acc[16];
    #pragma unroll
    for (int i = 0; i < 16; ++i) acc[i] = (f32x4){0.f,0.f,0.f,0.f};
    #pragma unroll
    for (int kk = 0; kk < 8; ++kk){
      #pragma unroll
      for (int nt = 0; nt < 16; ++nt){
        bf16x8 bf = *(const bf16x8*)(Bs + (nt*16 + (lane&15))*264 + kk*32 + (lane>>4)*8);
        acc[nt] = __builtin_amdgcn_mfma_f32_16x16x32_bf16(af[kk], bf, acc[nt], 0, 0, 0);
      }
    }
    int rowloc = w*16 + (lane>>4)*4;
    float sc[4]; size_t obase[4];
    #pragma unroll
    for (int i = 0; i < 4; ++i){
      int r = r0 + rowloc + i; int tt = r>>5, bb = r&31;
      sc[i] = ld_rlx(&pg[tt]) / Ssum[r];
      obase[i] = (size_t)(bb*Tn + tt)*VEn;
    }
    u64 pm[4] = {0,0,0,0};
    #pragma unroll
    for (int nt = 0; nt < 16; ++nt){
      int v = n0 + nt*16 + (lane&15);
      float b2v = b2[v];
      #pragma unroll
      for (int i = 0; i < 4; ++i){
        float val = __expf(acc[nt][i] + b2v) * sc[i];
        probs[obase[i] + v] = val;
        u64 p = ((u64)__float_as_uint(val)<<32) | (u64)(0xFFFFFFFFu - (unsigned)v);
        pm[i] = p > pm[i] ? p : pm[i];
      }
    }
    #pragma unroll
    for (int m = 1; m < 16; m <<= 1)
      #pragma unroll
      for (int i = 0; i < 4; ++i){
        u64 o = shfl_xor_u64(pm[i], m);
        pm[i] = o > pm[i] ? o : pm[i];
      }
    if ((lane&15) == 0)
      #pragma unroll
      for (int i = 0; i < 4; ++i)
        st_rlx64(&Ap[(size_t)slice*3200 + r0 + rowloc + i], pm[i]);
  }
}

// scatter copy-dist via LDS hash dedup + OOV zeros + fused argmax -> seqs.
__global__ __launch_bounds__(256) void k_scatter(const int* __restrict__ ext,
    const float* __restrict__ a_all, const float* __restrict__ pg,
    float* __restrict__ probs, const u64* __restrict__ Ap,
    float* __restrict__ seqs){
  __shared__ int   hkey[1024];
  __shared__ float hval[1024];
  __shared__ u64   wmax[4];
  int r = blockIdx.x; int t = r>>5, b = r&31;
  float c1 = 1.f - pg[t];
  int tid = threadIdx.x;
  #pragma unroll
  for (int i = 0; i < 4; ++i){
    hkey[tid + i*256] = -1;
    hval[tid + i*256] = 0.f;
  }
  size_t obase = (size_t)(b*Tn + t)*VEn;
  if (tid < OOVn) probs[obase + Vn + tid] = 0.f;
  u64 vm = (tid < 125) ? Ap[(size_t)tid*3200 + r] : 0ull;
  __syncthreads();
  for (int s = tid; s < Sn; s += 256){
    int key = ext[b*Sn + s];
    float v = c1 * a_all[(size_t)r*Sn + s];
    unsigned h = ((unsigned)key * 2654435761u) >> 22;   // 10 bits
    for (;;){
      int old = atomicCAS(&hkey[h], -1, key);
      if (old == -1 || old == key) break;
      h = (h + 1) & 1023;
    }
    atomicAdd(&hval[h], v);
  }
  __syncthreads();
  u64 pm = vm;
  #pragma unroll
  for (int i = 0; i < 4; ++i){
    int slot = tid + i*256;
    int tk = hkey[slot];
    if (tk >= 0){
      float nv = probs[obase + tk] + hval[slot];
      probs[obase + tk] = nv;
      u64 p = ((u64)__float_as_uint(nv)<<32) | (u64)(0xFFFFFFFFu - (unsigned)tk);
      pm = p > pm ? p : pm;
    }
  }
  #pragma unroll
  for (int m = 1; m < 64; m <<= 1){
    u64 o = shfl_xor_u64(pm, m);
    pm = o > pm ? o : pm;
  }
  int lane = tid & 63, w = tid >> 6;
  if (lane == 0) wmax[w] = pm;
  __syncthreads();
  if (tid == 0){
    u64 mm = wmax[0];
    #pragma unroll
    for (int q = 1; q < 4; ++q) mm = wmax[q] > mm ? wmax[q] : mm;
    unsigned tk = 0xFFFFFFFFu - (unsigned)(mm & 0xFFFFFFFFull);
    seqs[b*Tn + t] = (float)tk;
  }
}

// ---------------- host launch ----------------

extern "C" void kernel_launch(void* const* d_in, const int* in_sizes, int n_in,
                              void* d_out, int out_size, void* d_ws, size_t ws_size,
                              hipStream_t stream){
  (void)in_sizes; (void)n_in; (void)out_size; (void)ws_size;
  const int*   gt       = (const int*)d_in[0];
  const int*   ext      = (const int*)d_in[1];
  const float* enc_out  = (const float*)d_in[2];
  const float* enc_attn = (const float*)d_in[3];
  const float* h0       = (const float*)d_in[4];
  const float* c0       = (const float*)d_in[5];
  const float* emb      = (const float*)d_in[6];
  const float* Wk       = (const float*)d_in[7];
  const float* Wr       = (const float*)d_in[8];
  const float* lb       = (const float*)d_in[9];
  const float* Wd       = (const float*)d_in[10];
  const float* bd       = (const float*)d_in[11];
  const float* Wc       = (const float*)d_in[12];
  const float* Wa       = (const float*)d_in[13];
  const float* W1       = (const float*)d_in[14];
  const float* b1       = (const float*)d_in[15];
  const float* W2       = (const float*)d_in[16];
  const float* b2       = (const float*)d_in[17];
  const float* gpWs     = (const float*)d_in[18];
  const float* gpWc     = (const float*)d_in[19];
  const float* gpWi     = (const float*)d_in[20];
  const float* gpbi     = (const float*)d_in[21];
  const float* gpWg     = (const float*)d_in[22];

  float* probs   = (float*)d_out;
  float* seqs    = probs + (size_t)Bn*Tn*VEn;
  float* covloss = seqs + Bn*Tn;

  char* wp = (char*)d_ws;
  auto carve = [&](size_t bytes)->void*{
    void* p = (void*)wp; wp += (bytes + 255) & ~(size_t)255; return p;
  };
  float*    Zx      = (float*)carve((size_t)3200*Z4n*4);
  float*    h_all   = (float*)carve((size_t)Tn*Bn*Un*4);
  float*    decp    = (float*)carve((size_t)2*Bn*8*256*4);
  float*    c0_all  = (float*)carve((size_t)Tn*Un*4);
  float*    a_all   = (float*)carve((size_t)3200*Sn*4);
  ushort_t* hid_bf  = (ushort_t*)carve((size_t)3200*Un*2);
  ushort_t* W2T     = (ushort_t*)carve((size_t)Vn*Un*2);
  float*    Ssum    = (float*)carve((size_t)3200*4);
  float*    Sp      = (float*)carve((size_t)125*3200*4);
  u64*      Ap      = (u64*)carve((size_t)125*3200*8);
  float*    pg      = (float*)carve((size_t)Tn*4);
  float*    spart   = (float*)carve((size_t)2*Bn*8*4);
  unsigned* bars    = (unsigned*)carve((size_t)Bn*8*32*4);
  unsigned* bars2   = (unsigned*)carve((size_t)NPB*32*4);

  k_zx  <<<dim3(50,16), 256, 0, stream>>>(gt, emb, Wk, lb, Zx,
                                          bars, bars2, covloss);

  k_loop<<<256, 1024, 0, stream>>>(Zx, Wr, Wd, bd, Wc, Wa, enc_attn,
                                   h0, c0, h_all, decp, c0_all,
                                   a_all, covloss, spart, bars);

  k_post<<<NPB, 512, 0, stream>>>(h_all, W1, b1, hid_bf, gt, emb,
                                  gpWi, gpbi, a_all, enc_out, c0_all,
                                  gpWs, gpWc, gpWg, pg, W2, W2T, b2,
                                  Sp, Ssum, Ap, probs, bars2);

  k_scatter<<<3200, 256, 0, stream>>>(ext, a_all, pg, probs, Ap, seqs);
}